// Round 18
// baseline (397.290 us; speedup 1.0000x reference)
//
#include <hip/hip_runtime.h>
#include <hip/hip_bf16.h>

typedef unsigned short ushort;
typedef __attribute__((ext_vector_type(8))) __bf16 bf16x8;
typedef __attribute__((ext_vector_type(4))) float f32x4;
typedef __attribute__((ext_vector_type(8))) ushort ushort8;

__device__ inline ushort f2bf(float f) {
    union { float f; unsigned u; } a{f};
    unsigned r = a.u + 0x7FFFu + ((a.u >> 16) & 1u);
    return (ushort)(r >> 16);
}
__device__ inline float gelu_f(float x) {
    return 0.5f * x * (1.f + erff(x * 0.70710678118654752f));
}

// ---------------- fused prologue: transposes + rowstat + precomp + init ----
__global__ void prep_all(const float* __restrict__ se_w2, ushort* __restrict__ sw2t,
                         const float* __restrict__ wq, ushort* __restrict__ wqt,
                         const float* __restrict__ wk, ushort* __restrict__ wkt,
                         const float* __restrict__ wv, ushort* __restrict__ wvt,
                         const float* __restrict__ wo, ushort* __restrict__ wot,
                         const float* __restrict__ gw1, ushort* __restrict__ g1t,
                         const float* __restrict__ gw2, ushort* __restrict__ g2t,
                         const float* __restrict__ x, ushort* __restrict__ xb,
                         float* __restrict__ sq,
                         const float* __restrict__ bq, const float* __restrict__ bk,
                         const float* __restrict__ bv, float* __restrict__ bqkv,
                         float* __restrict__ meanv,
                         const float* __restrict__ dp_w, const float* __restrict__ dp_b,
                         const float* __restrict__ se_w1, const float* __restrict__ se_b1,
                         float* __restrict__ Avec, float* __restrict__ Cvec) {
    __shared__ float tile[32][33];
    __shared__ float wsum[4];
    int bid = blockIdx.x;
    int tid = threadIdx.x;
    if (bid < 7488) {
        const float* Wm; ushort* Wt; int K, N, kx, ny;
        if (bid < 2880) {
            int task = bid / 576, tt = bid % 576;
            kx = tt % 24; ny = tt / 24; K = 768; N = 768;
            switch (task) {
                case 0: Wm = se_w2; Wt = sw2t; break;
                case 1: Wm = wq; Wt = wqt; break;
                case 2: Wm = wk; Wt = wkt; break;
                case 3: Wm = wv; Wt = wvt; break;
                default: Wm = wo; Wt = wot; break;
            }
        } else if (bid < 5184) {
            int tt = bid - 2880; kx = tt % 24; ny = tt / 24; K = 768; N = 3072;
            Wm = gw1; Wt = g1t;
        } else {
            int tt = bid - 5184; kx = tt % 96; ny = tt / 96; K = 3072; N = 768;
            Wm = gw2; Wt = g2t;
        }
        int k0 = kx * 32, n0 = ny * 32;
        int tx = tid & 31, ty = tid >> 5;
        #pragma unroll
        for (int r = ty; r < 32; r += 8) tile[r][tx] = Wm[(size_t)(k0 + r) * N + n0 + tx];
        __syncthreads();
        #pragma unroll
        for (int r = ty; r < 32; r += 8) Wt[(size_t)(n0 + r) * K + k0 + tx] = f2bf(tile[tx][r]);
    } else if (bid < 15680) {
        int row = bid - 7488;
        const float* xr = x + (size_t)row * 768;
        ushort* xbr = xb + (size_t)row * 768;
        float s = 0.f;
        #pragma unroll
        for (int i = 0; i < 3; ++i) {
            float vv = xr[tid + i * 256];
            xbr[tid + i * 256] = f2bf(vv);
            s += vv * vv;
        }
        #pragma unroll
        for (int off = 1; off < 64; off <<= 1) s += __shfl_xor(s, off);
        if ((tid & 63) == 0) wsum[tid >> 6] = s;
        __syncthreads();
        if (tid == 0) sq[row] = wsum[0] + wsum[1] + wsum[2] + wsum[3];
    } else if (bid < 15683) {
        int o = (bid - 15680) * 256 + tid;
        float a = 0.f, c = 0.f;
        for (int i = 0; i < 192; ++i) {
            float w = se_w1[(size_t)i * 768 + o];
            a += dp_w[i] * w;
            c += dp_b[i] * w;
        }
        Avec[o] = a;
        Cvec[o] = c + se_b1[o];
    } else if (bid < 15715) {
        meanv[(bid - 15683) * 256 + tid] = 0.f;
    } else {
        for (int i = tid; i < 2304; i += 256) {
            float v = (i < 768) ? bq[i] : (i < 1536 ? bk[i - 768] : bv[i - 1536]);
            bqkv[i] = v;
        }
    }
}

// ---------------- spatial h generation (rank-1 + gelu) ---------------------
__global__ void hgen(const float* __restrict__ mean_acc, const float* __restrict__ Avec,
                     const float* __restrict__ Cvec, ushort* __restrict__ h) {
    int row = blockIdx.x;
    float md = mean_acc[row] * (1.f / 1024.f);
    int t = threadIdx.x;
    #pragma unroll
    for (int i = 0; i < 3; ++i) {
        int o = t + i * 256;
        h[(size_t)row * 768 + o] = f2bf(gelu_f(md * Avec[o] + Cvec[o]));
    }
}

// ---------------- layernorm fp32 -> bf16 -----------------------------------
__global__ void lnorm(const float* __restrict__ xin, const float* __restrict__ g,
                      const float* __restrict__ b, ushort* __restrict__ xn) {
    int row = blockIdx.x;
    const float* xr = xin + (size_t)row * 768;
    int t = threadIdx.x;
    float v[3];
    float s = 0.f, s2 = 0.f;
    #pragma unroll
    for (int i = 0; i < 3; ++i) {
        v[i] = xr[t + i * 256];
        s += v[i];
        s2 += v[i] * v[i];
    }
    #pragma unroll
    for (int off = 1; off < 64; off <<= 1) { s += __shfl_xor(s, off); s2 += __shfl_xor(s2, off); }
    __shared__ float a0[4], a1[4];
    if ((t & 63) == 0) { a0[t >> 6] = s; a1[t >> 6] = s2; }
    __syncthreads();
    s = a0[0] + a0[1] + a0[2] + a0[3];
    s2 = a1[0] + a1[1] + a1[2] + a1[3];
    float mu = s * (1.f / 768.f);
    float var = s2 * (1.f / 768.f) - mu * mu;
    float rs = rsqrtf(var + 1e-5f);
    #pragma unroll
    for (int i = 0; i < 3; ++i) {
        int o = t + i * 256;
        xn[(size_t)row * 768 + o] = f2bf((v[i] - mu) * rs * g[o] + b[o]);
    }
}

// ---------------- MFMA GEMM (2-phase, 128-tile): used for Gram only --------
#define BM 128
#define BK 32

enum { EPI_BF16 = 0, EPI_GELU = 1, EPI_RES = 2, EPI_GRAM = 3, EPI_QKV = 4 };

template <int EPI, int BNT>
__launch_bounds__(256, BNT == 64 ? 4 : 2)
__global__ void gemm_bt(const ushort* __restrict__ A, const ushort* __restrict__ Bt,
                        int M, int N, int K,
                        const float* __restrict__ bias,
                        const float* res, float* outf,
                        ushort* __restrict__ outh,
                        const float* __restrict__ sq, float* __restrict__ mean_acc) {
    __shared__ __align__(16) ushort As[2][BM * BK];
    __shared__ __align__(16) ushort Bs[2][BNT * BK];

    unsigned gx = gridDim.x, gy = gridDim.y;
    unsigned flat = blockIdx.x + gx * (blockIdx.y + gy * blockIdx.z);
    unsigned total = gx * gy * gridDim.z;
    unsigned chunk = total >> 3;
    flat = (flat & 7) * chunk + (flat >> 3);
    unsigned bx = flat % gx;
    unsigned rem = flat / gx;
    unsigned by = rem % gy;
    unsigned bz = rem / gy;

    int m0 = bx * BM;
    int n0 = by * BNT;
    if (EPI == EPI_GRAM) {
        A += (size_t)bz * 1024 * 768;
        Bt = A;
        sq += bz * 1024;
        mean_acc += bz * 1024;
    }
    int t = threadIdx.x, w = t >> 6, l = t & 63;
    int lg = l >> 4, li = l & 15;
    constexpr int MI = (BNT == 128) ? 4 : 2;
    int wm = (BNT == 128) ? (w >> 1) * 64 : w * 32;
    int wn = (BNT == 128) ? (w & 1) * 64 : 0;

    int srow = l >> 2, scol = (l & 3) * 8;
    const ushort* agp0 = A + (size_t)(m0 + (2 * w) * 16 + srow) * K + scol;
    const ushort* agp1 = A + (size_t)(m0 + (2 * w + 1) * 16 + srow) * K + scol;
    const ushort* bgp0;
    const ushort* bgp1 = nullptr;
    ushort* la0 = &As[0][(2 * w) * 16 * BK];
    ushort* lb0;
    if (BNT == 128) {
        bgp0 = Bt + (size_t)(n0 + (2 * w) * 16 + srow) * K + scol;
        bgp1 = Bt + (size_t)(n0 + (2 * w + 1) * 16 + srow) * K + scol;
        lb0 = &Bs[0][(2 * w) * 16 * BK];
    } else {
        bgp0 = Bt + (size_t)(n0 + w * 16 + srow) * K + scol;
        lb0 = &Bs[0][w * 16 * BK];
    }

    f32x4 acc[MI][4] = {};

    auto stage = [&](int buf, int kt) {
        size_t ko = (size_t)kt * BK;
        ushort* la = la0 + buf * (BM * BK);
        ushort* lb = lb0 + buf * (BNT * BK);
        __builtin_amdgcn_global_load_lds((const __attribute__((address_space(1))) void*)(agp0 + ko),
                                         (__attribute__((address_space(3))) void*)la, 16, 0, 0);
        __builtin_amdgcn_global_load_lds((const __attribute__((address_space(1))) void*)(agp1 + ko),
                                         (__attribute__((address_space(3))) void*)(la + 16 * BK), 16, 0, 0);
        __builtin_amdgcn_global_load_lds((const __attribute__((address_space(1))) void*)(bgp0 + ko),
                                         (__attribute__((address_space(3))) void*)lb, 16, 0, 0);
        if (BNT == 128)
            __builtin_amdgcn_global_load_lds((const __attribute__((address_space(1))) void*)(bgp1 + ko),
                                             (__attribute__((address_space(3))) void*)(lb + 16 * BK), 16, 0, 0);
    };

    int nk = K / BK;
    stage(0, 0);
    __syncthreads();
    int buf = 0;
    for (int kt = 0; kt < nk; ++kt) {
        if (kt + 1 < nk) stage(buf ^ 1, kt + 1);
        bf16x8 af[MI], bfr[4];
        #pragma unroll
        for (int i = 0; i < MI; ++i)
            af[i] = *reinterpret_cast<const bf16x8*>(&As[buf][(wm + i * 16 + li) * BK + lg * 8]);
        #pragma unroll
        for (int i = 0; i < 4; ++i)
            bfr[i] = *reinterpret_cast<const bf16x8*>(&Bs[buf][(wn + i * 16 + li) * BK + lg * 8]);
        #pragma unroll
        for (int mi = 0; mi < MI; ++mi)
            #pragma unroll
            for (int ni = 0; ni < 4; ++ni)
                acc[mi][ni] = __builtin_amdgcn_mfma_f32_16x16x32_bf16(af[mi], bfr[ni], acc[mi][ni], 0, 0, 0);
        __syncthreads();
        buf ^= 1;
    }

    #pragma unroll
    for (int mi = 0; mi < MI; ++mi) {
        #pragma unroll
        for (int r = 0; r < 4; ++r) {
            int row = m0 + wm + mi * 16 + lg * 4 + r;
            if (EPI == EPI_GRAM) {
                float si = sq[row];
                float s = 0.f;
                #pragma unroll
                for (int ni = 0; ni < 4; ++ni) {
                    int col = n0 + wn + ni * 16 + li;
                    float d2 = si + sq[col] - 2.f * acc[mi][ni][r];
                    s += sqrtf(fmaxf(d2, 0.f));
                }
                s += __shfl_xor(s, 1); s += __shfl_xor(s, 2);
                s += __shfl_xor(s, 4); s += __shfl_xor(s, 8);
                if (li == 0) atomicAdd(&mean_acc[row], s);
            } else {
                #pragma unroll
                for (int ni = 0; ni < 4; ++ni) {
                    int col = n0 + wn + ni * 16 + li;
                    float v = acc[mi][ni][r] + bias[col];
                    if (EPI == EPI_BF16) outh[(size_t)row * N + col] = f2bf(v);
                    if (EPI == EPI_GELU) outh[(size_t)row * N + col] = f2bf(gelu_f(v));
                    if (EPI == EPI_RES) outf[(size_t)row * N + col] = res[(size_t)row * N + col] + v;
                    if (EPI == EPI_QKV) {
                        int which = col / 768;
                        int c2 = col - which * 768;
                        outh[(size_t)which * (8192 * 768) + (size_t)row * 768 + c2] = f2bf(v);
                    }
                }
            }
        }
    }
}

// ---------------- gemm4p: 128x128, m-split XCD, 3 blocks/CU, PIPELINED -----
// Used for K=768 GEMMs (se_w2, QKV, wo, FFN1). Conflicts measured 0.
template <int EPI>
__launch_bounds__(256, 3)
__global__ void gemm4(const ushort* __restrict__ A, const ushort* __restrict__ Bt,
                      int M, int N, int K,
                      const float* __restrict__ bias,
                      const float* res, float* outf, ushort* __restrict__ outh) {
    __shared__ __align__(16) ushort As[3][128 * 32];
    __shared__ __align__(16) ushort Bs[3][128 * 32];

    unsigned gx = gridDim.x, gy = gridDim.y;
    unsigned orig = blockIdx.x + gx * (blockIdx.y + gy * blockIdx.z);
    unsigned xcd = orig & 7;
    unsigned q = orig >> 3;
    unsigned mpg = gx >> 3;
    unsigned mloc = q % mpg;
    unsigned rest = q / mpg;
    unsigned n = rest % gy;
    int m0 = (xcd * mpg + mloc) * 128;
    int n0 = n * 128;

    int t = threadIdx.x, w = t >> 6, l = t & 63;
    int lg = l >> 4, li = l & 15;
    int wm = (w >> 1) * 64, wn = (w & 1) * 64;

    int srow = l >> 2;
    int scol = ((l & 3) ^ ((l >> 3) & 3)) * 8;
    const ushort* agp0 = A + (size_t)(m0 + (2 * w) * 16 + srow) * K + scol;
    const ushort* agp1 = A + (size_t)(m0 + (2 * w + 1) * 16 + srow) * K + scol;
    const ushort* bgp0 = Bt + (size_t)(n0 + (2 * w) * 16 + srow) * K + scol;
    const ushort* bgp1 = Bt + (size_t)(n0 + (2 * w + 1) * 16 + srow) * K + scol;

    f32x4 acc[4][4] = {};

    auto stage = [&](int buf, int kt) {
        size_t ko = (size_t)kt * 32;
        ushort* la = &As[buf][(2 * w) * 16 * 32];
        ushort* lb = &Bs[buf][(2 * w) * 16 * 32];
        __builtin_amdgcn_global_load_lds((const __attribute__((address_space(1))) void*)(agp0 + ko),
                                         (__attribute__((address_space(3))) void*)la, 16, 0, 0);
        __builtin_amdgcn_global_load_lds((const __attribute__((address_space(1))) void*)(agp1 + ko),
                                         (__attribute__((address_space(3))) void*)(la + 16 * 32), 16, 0, 0);
        __builtin_amdgcn_global_load_lds((const __attribute__((address_space(1))) void*)(bgp0 + ko),
                                         (__attribute__((address_space(3))) void*)lb, 16, 0, 0);
        __builtin_amdgcn_global_load_lds((const __attribute__((address_space(1))) void*)(bgp1 + ko),
                                         (__attribute__((address_space(3))) void*)(lb + 16 * 32), 16, 0, 0);
    };

    int nk = K / 32;
    stage(0, 0);
    stage(1, 1);
    int rdsw = (lg ^ ((li >> 1) & 3)) * 8;
    for (int kt = 0; kt < nk; ++kt) {
        int buf = kt % 3;
        if (kt + 1 < nk) asm volatile("s_waitcnt vmcnt(4)" ::: "memory");
        else             asm volatile("s_waitcnt vmcnt(0)" ::: "memory");
        asm volatile("s_barrier" ::: "memory");
        __builtin_amdgcn_sched_barrier(0);
        bf16x8 af[4], bfr[4];
        #pragma unroll
        for (int i = 0; i < 4; ++i) {
            af[i] = *reinterpret_cast<const bf16x8*>(&As[buf][(wm + i * 16 + li) * 32 + rdsw]);
            bfr[i] = *reinterpret_cast<const bf16x8*>(&Bs[buf][(wn + i * 16 + li) * 32 + rdsw]);
        }
        __builtin_amdgcn_s_setprio(1);
        #pragma unroll
        for (int mi = 0; mi < 4; ++mi)
            #pragma unroll
            for (int ni = 0; ni < 4; ++ni)
                acc[mi][ni] = __builtin_amdgcn_mfma_f32_16x16x32_bf16(af[mi], bfr[ni], acc[mi][ni], 0, 0, 0);
        __builtin_amdgcn_s_setprio(0);
        if (kt + 2 < nk) stage((kt + 2) % 3, kt + 2);
    }

    #pragma unroll
    for (int mi = 0; mi < 4; ++mi) {
        #pragma unroll
        for (int r = 0; r < 4; ++r) {
            int row = m0 + wm + mi * 16 + lg * 4 + r;
            #pragma unroll
            for (int ni = 0; ni < 4; ++ni) {
                int col = n0 + wn + ni * 16 + li;
                float v = acc[mi][ni][r] + bias[col];
                if (EPI == EPI_GELU) outh[(size_t)row * N + col] = f2bf(gelu_f(v));
                if (EPI == EPI_RES)  outf[(size_t)row * N + col] = res[(size_t)row * N + col] + v;
                if (EPI == EPI_QKV) {
                    int which = col / 768;
                    int c2 = col - which * 768;
                    outh[(size_t)which * (8192 * 768) + (size_t)row * 768 + c2] = f2bf(v);
                }
            }
        }
    }
}

// ---------------- gemm8 (r12-proven, 81.7us on FFN2): 256x128, BK=64 -------
// M-split XCD mapping; 3-bit LDS XOR swizzle both-sides (conflicts = 0);
// counted vmcnt 12/6/0; setprio. Used for FFN2 (K=3072) only.
template <int EPI>
__launch_bounds__(512, 2)
__global__ void gemm8(const ushort* __restrict__ A, const ushort* __restrict__ Bt,
                      int M, int N, int K,
                      const float* __restrict__ bias,
                      const float* res, float* outf, ushort* __restrict__ outh) {
    __shared__ __align__(16) ushort As[3][2][128 * 64];
    __shared__ __align__(16) ushort Bs[3][2][64 * 64];

    unsigned gx = gridDim.x;                       // 32 m-tiles
    unsigned orig = blockIdx.x + gx * blockIdx.y;
    unsigned xcd = orig & 7;
    unsigned q = orig >> 3;
    unsigned mpg = gx >> 3;                        // 4 m-tiles per XCD
    unsigned mloc = q % mpg;
    unsigned n = q / mpg;
    int m0 = (xcd * mpg + mloc) * 256;
    int n0 = n * 128;

    int t = threadIdx.x, w = t >> 6, l = t & 63;
    int lg = l >> 4, li = l & 15;
    int wr = w >> 1, wc = w & 1;
    int ha = wr >> 1;
    int ra = (wr & 1) * 64;

    f32x4 acc[4][4] = {};

    auto stage = [&](int buf, int kt) {
        int k0 = kt * 64;
        #pragma unroll
        for (int h = 0; h < 2; ++h) {
            #pragma unroll
            for (int jj = 0; jj < 2; ++jj) {
                int d = (2 * w + jj) * 1024 + l * 16;
                int dp = d ^ (((d >> 7) & 7) << 4);
                const ushort* src = A + (size_t)(m0 + h * 128 + (dp >> 7)) * K + k0 + ((dp & 127) >> 1);
                __builtin_amdgcn_global_load_lds(
                    (const __attribute__((address_space(1))) void*)src,
                    (__attribute__((address_space(3))) void*)&As[buf][h][(2 * w + jj) * 512], 16, 0, 0);
            }
            {
                int d = w * 1024 + l * 16;
                int dp = d ^ (((d >> 7) & 7) << 4);
                const ushort* src = Bt + (size_t)(n0 + h * 64 + (dp >> 7)) * K + k0 + ((dp & 127) >> 1);
                __builtin_amdgcn_global_load_lds(
                    (const __attribute__((address_space(1))) void*)src,
                    (__attribute__((address_space(3))) void*)&Bs[buf][h][w * 512], 16, 0, 0);
            }
        }
    };

    int nk = K / 64;
    stage(0, 0);
    stage(1, 1);
    stage(2, 2);
    for (int kt = 0; kt < nk; ++kt) {
        int buf = kt % 3;
        if (kt + 2 < nk)      asm volatile("s_waitcnt vmcnt(12)" ::: "memory");
        else if (kt + 1 < nk) asm volatile("s_waitcnt vmcnt(6)" ::: "memory");
        else                  asm volatile("s_waitcnt vmcnt(0)" ::: "memory");
        asm volatile("s_barrier" ::: "memory");
        __builtin_amdgcn_sched_barrier(0);
        #pragma unroll
        for (int kk = 0; kk < 2; ++kk) {
            bf16x8 af[4], bf[4];
            #pragma unroll
            for (int mi = 0; mi < 4; ++mi) {
                int e = (ra + mi * 16 + li) * 128 + kk * 64 + lg * 16;
                int ep = e ^ (((e >> 7) & 7) << 4);
                af[mi] = *reinterpret_cast<const bf16x8*>(&As[buf][ha][ep >> 1]);
            }
            #pragma unroll
            for (int ni = 0; ni < 4; ++ni) {
                int e = (ni * 16 + li) * 128 + kk * 64 + lg * 16;
                int ep = e ^ (((e >> 7) & 7) << 4);
                bf[ni] = *reinterpret_cast<const bf16x8*>(&Bs[buf][wc][ep >> 1]);
            }
            __builtin_amdgcn_s_setprio(1);
            #pragma unroll
            for (int mi = 0; mi < 4; ++mi)
                #pragma unroll
                for (int ni = 0; ni < 4; ++ni)
                    acc[mi][ni] = __builtin_amdgcn_mfma_f32_16x16x32_bf16(af[mi], bf[ni], acc[mi][ni], 0, 0, 0);
            __builtin_amdgcn_s_setprio(0);
        }
        asm volatile("s_barrier" ::: "memory");
        __builtin_amdgcn_sched_barrier(0);
        if (kt + 3 < nk) stage(buf, kt + 3);
    }

    #pragma unroll
    for (int mi = 0; mi < 4; ++mi) {
        #pragma unroll
        for (int r = 0; r < 4; ++r) {
            int row = m0 + wr * 64 + mi * 16 + lg * 4 + r;
            #pragma unroll
            for (int ni = 0; ni < 4; ++ni) {
                int col = n0 + wc * 64 + ni * 16 + li;
                float v = acc[mi][ni][r] + bias[col];
                if (EPI == EPI_GELU) outh[(size_t)row * N + col] = f2bf(gelu_f(v));
                if (EPI == EPI_RES)  outf[(size_t)row * N + col] = res[(size_t)row * N + col] + v;
            }
        }
    }
}

// ---------------- flash attention v10: log2-domain softmax -----------------
// grid (8, 12, 8); 4 waves; K via global_load_lds dbuf; ones-MFMA ell;
// defer-max; setprio. Softmax in log2 domain: v_exp_f32 IS 2^x, so folding
// 0.125*log2e into the S scale removes the hidden per-exp multiply
// (64 VALU muls/iter/wave). Threshold 8 -> 8*log2e = 11.5416.
__launch_bounds__(256, 3)
__global__ void flash_attn(const ushort* __restrict__ q, const ushort* __restrict__ k,
                           const ushort* __restrict__ v, ushort* __restrict__ o) {
    int flat = blockIdx.x + 8 * (blockIdx.y + 12 * blockIdx.z);
    flat = (flat & 7) * 96 + (flat >> 3);
    int qt = flat & 7;
    int rem = flat >> 3;
    int h = rem % 12;
    int b = rem / 12;

    int t = threadIdx.x, w = t >> 6, l = t & 63;
    int lg = l >> 4, li = l & 15;

    __shared__ __align__(16) ushort Vt[2][64][72];  // V^T tile, stride 144B
    __shared__ __align__(16) ushort P[4][32][72];   // per-wave P[q][kv]
    __shared__ __align__(16) ushort Ks[2][64 * 64]; // K tile, chunk-swizzled

    const size_t hoff = (size_t)h * 64;
    const size_t bbase = (size_t)b * 1024 * 768;
    const ushort* kbase = &k[bbase + hoff];

    bf16x8 qf[2][2];
    #pragma unroll
    for (int f = 0; f < 2; ++f) {
        int qrow = qt * 128 + w * 32 + f * 16 + li;
        const ushort* qp = &q[bbase + (size_t)qrow * 768 + hoff];
        qf[f][0] = *reinterpret_cast<const bf16x8*>(qp + lg * 8);
        qf[f][1] = *reinterpret_cast<const bf16x8*>(qp + 32 + lg * 8);
    }

    bf16x8 onesf;
    #pragma unroll
    for (int i = 0; i < 8; ++i) onesf[i] = (__bf16)1.0f;

    const float SSC = 0.125f * 1.44269504088896f;  // 1/8 * log2(e)
    const float THR = 8.f * 1.44269504088896f;     // defer-max threshold, log2 units

    float m_[2][4];
    f32x4 oacc[2][4];
    f32x4 oell[2];
    #pragma unroll
    for (int f = 0; f < 2; ++f) {
        #pragma unroll
        for (int r = 0; r < 4; ++r) m_[f][r] = -1e30f;
        oell[f] = f32x4{0.f, 0.f, 0.f, 0.f};
        #pragma unroll
        for (int n = 0; n < 4; ++n) oacc[f][n] = f32x4{0.f, 0.f, 0.f, 0.f};
    }

    int vrow = t & 63;
    int vc = t >> 6;
    const ushort* vbase = &v[bbase + hoff];

    auto stageK = [&](int kbuf, int jtile) {
        #pragma unroll
        for (int j = 0; j < 2; ++j) {
            int c = (w * 2 + j) * 64 + l;
            int krow = c >> 3, kcc = c & 7;
            int srcc = (kcc & 4) | ((kcc & 3) ^ (krow & 3));
            const ushort* src = &kbase[(size_t)(jtile * 64 + krow) * 768 + srcc * 8];
            __builtin_amdgcn_global_load_lds(
                (const __attribute__((address_space(1))) void*)src,
                (__attribute__((address_space(3))) void*)&Ks[kbuf][c * 8], 16, 0, 0);
        }
    };

    stageK(0, 0);
    ushort8 vv0 = *reinterpret_cast<const ushort8*>(&vbase[(size_t)vrow * 768 + vc * 8]);
    ushort8 vv1 = *reinterpret_cast<const ushort8*>(&vbase[(size_t)vrow * 768 + (vc + 4) * 8]);
    __syncthreads();

    int kch = lg ^ (li & 3);

    for (int jt = 0; jt < 16; ++jt) {
        int j0 = jt * 64, buf = jt & 1;
        #pragma unroll
        for (int i = 0; i < 8; ++i) Vt[buf][vc * 8 + i][vrow] = vv0[i];
        #pragma unroll
        for (int i = 0; i < 8; ++i) Vt[buf][(vc + 4) * 8 + i][vrow] = vv1[i];
        if (jt < 15) {
            vv0 = *reinterpret_cast<const ushort8*>(&vbase[(size_t)(j0 + 64 + vrow) * 768 + vc * 8]);
            vv1 = *reinterpret_cast<const ushort8*>(&vbase[(size_t)(j0 + 64 + vrow) * 768 + (vc + 4) * 8]);
            stageK(buf ^ 1, jt + 1);
        }
        f32x4 s[2][4];
        __builtin_amdgcn_s_setprio(1);
        #pragma unroll
        for (int jj = 0; jj < 4; ++jj) {
            int krow = jj * 16 + li;
            bf16x8 kf0 = *reinterpret_cast<const bf16x8*>(&Ks[buf][krow * 64 + kch * 8]);
            bf16x8 kf1 = *reinterpret_cast<const bf16x8*>(&Ks[buf][krow * 64 + 32 + kch * 8]);
            #pragma unroll
            for (int f = 0; f < 2; ++f) {
                f32x4 a = {0.f, 0.f, 0.f, 0.f};
                a = __builtin_amdgcn_mfma_f32_16x16x32_bf16(qf[f][0], kf0, a, 0, 0, 0);
                a = __builtin_amdgcn_mfma_f32_16x16x32_bf16(qf[f][1], kf1, a, 0, 0, 0);
                s[f][jj] = a * SSC;     // log2-domain scores
            }
        }
        __builtin_amdgcn_s_setprio(0);
        #pragma unroll
        for (int f = 0; f < 2; ++f) {
            float mt[4];
            #pragma unroll
            for (int r = 0; r < 4; ++r)
                mt[r] = fmaxf(fmaxf(s[f][0][r], s[f][1][r]), fmaxf(s[f][2][r], s[f][3][r]));
            #pragma unroll
            for (int r = 0; r < 4; ++r) {
                mt[r] = fmaxf(mt[r], __shfl_xor(mt[r], 1));
                mt[r] = fmaxf(mt[r], __shfl_xor(mt[r], 2));
                mt[r] = fmaxf(mt[r], __shfl_xor(mt[r], 4));
                mt[r] = fmaxf(mt[r], __shfl_xor(mt[r], 8));
            }
            bool need = (mt[0] > m_[f][0] + THR) | (mt[1] > m_[f][1] + THR) |
                        (mt[2] > m_[f][2] + THR) | (mt[3] > m_[f][3] + THR);
            if (__any(need)) {
                #pragma unroll
                for (int r = 0; r < 4; ++r) {
                    float mn = fmaxf(m_[f][r], mt[r]);
                    float al = exp2f(m_[f][r] - mn);
                    m_[f][r] = mn;
                    #pragma unroll
                    for (int n = 0; n < 4; ++n) oacc[f][n][r] *= al;
                    oell[f][r] *= al;
                }
            }
            #pragma unroll
            for (int jj = 0; jj < 4; ++jj)
                #pragma unroll
                for (int r = 0; r < 4; ++r)
                    P[w][f * 16 + lg * 4 + r][jj * 16 + li] = f2bf(exp2f(s[f][jj][r] - m_[f][r]));
        }
        __syncthreads();   // drains K-DMA for jt+1; orders Vt/P
        bf16x8 pf[2][2];
        #pragma unroll
        for (int f = 0; f < 2; ++f) {
            pf[f][0] = *reinterpret_cast<const bf16x8*>(&P[w][f * 16 + li][lg * 8]);
            pf[f][1] = *reinterpret_cast<const bf16x8*>(&P[w][f * 16 + li][32 + lg * 8]);
        }
        __builtin_amdgcn_s_setprio(1);
        #pragma unroll
        for (int f = 0; f < 2; ++f) {
            oell[f] = __builtin_amdgcn_mfma_f32_16x16x32_bf16(pf[f][0], onesf, oell[f], 0, 0, 0);
            oell[f] = __builtin_amdgcn_mfma_f32_16x16x32_bf16(pf[f][1], onesf, oell[f], 0, 0, 0);
        }
        #pragma unroll
        for (int n = 0; n < 4; ++n) {
            bf16x8 vf0 = *reinterpret_cast<const bf16x8*>(&Vt[buf][n * 16 + li][lg * 8]);
            bf16x8 vf1 = *reinterpret_cast<const bf16x8*>(&Vt[buf][n * 16 + li][32 + lg * 8]);
            #pragma unroll
            for (int f = 0; f < 2; ++f) {
                oacc[f][n] = __builtin_amdgcn_mfma_f32_16x16x32_bf16(pf[f][0], vf0, oacc[f][n], 0, 0, 0);
                oacc[f][n] = __builtin_amdgcn_mfma_f32_16x16x32_bf16(pf[f][1], vf1, oacc[f][n], 0, 0, 0);
            }
        }
        __builtin_amdgcn_s_setprio(0);
    }
    #pragma unroll
    for (int f = 0; f < 2; ++f)
        #pragma unroll
        for (int n = 0; n < 4; ++n)
            #pragma unroll
            for (int r = 0; r < 4; ++r) {
                int row = qt * 128 + w * 32 + f * 16 + lg * 4 + r;
                o[bbase + (size_t)row * 768 + hoff + n * 16 + li] = f2bf(oacc[f][n][r] / oell[f][r]);
            }
}

// ---------------------------------------------------------------------------
extern "C" void kernel_launch(void* const* d_in, const int* in_sizes, int n_in,
                              void* d_out, int out_size, void* d_ws, size_t ws_size,
                              hipStream_t stream) {
    const float* x = (const float*)d_in[0];
    const float* dp_w = (const float*)d_in[1];
    const float* dp_b = (const float*)d_in[2];
    const float* se_w1 = (const float*)d_in[3];
    const float* se_b1 = (const float*)d_in[4];
    const float* se_w2 = (const float*)d_in[5];
    const float* se_b2 = (const float*)d_in[6];
    const float* wq = (const float*)d_in[7];  const float* bq = (const float*)d_in[8];
    const float* wk = (const float*)d_in[9];  const float* bk = (const float*)d_in[10];
    const float* wv = (const float*)d_in[11]; const float* bv = (const float*)d_in[12];
    const float* wo = (const float*)d_in[13]; const float* bo = (const float*)d_in[14];
    const float* gw1 = (const float*)d_in[15]; const float* gb1 = (const float*)d_in[16];
    const float* gw2 = (const float*)d_in[17]; const float* gb2 = (const float*)d_in[18];
    const float* n1g = (const float*)d_in[19]; const float* n1b = (const float*)d_in[20];
    const float* n2g = (const float*)d_in[21]; const float* n2b = (const float*)d_in[22];
    float* out = (float*)d_out;

    constexpr size_t SZ_ACT = (size_t)8192 * 768 * 2;  // bytes per bf16 activation
    char* W = (char*)d_ws;
    ushort* xb = (ushort*)(W);                  // bf16 x; later reused as xn
    ushort* q_ = (ushort*)(W + SZ_ACT);
    ushort* k_ = (ushort*)(W + 2 * SZ_ACT);
    ushort* v_ = (ushort*)(W + 3 * SZ_ACT);
    ushort* o_ = (ushort*)(W + 4 * SZ_ACT);
    ushort* hsp = q_;
    ushort* hff = q_;
    ushort* wqt = (ushort*)(W + 5 * SZ_ACT);    // contiguous qkv weight [2304][768]
    ushort* wkt = wqt + (size_t)768 * 768;
    ushort* wvt = wkt + (size_t)768 * 768;
    ushort* wot = wvt + (size_t)768 * 768;
    ushort* sw2t = wot + (size_t)768 * 768;
    ushort* g1t = sw2t + (size_t)768 * 768;
    ushort* g2t = g1t + (size_t)768 * 3072;
    float* sqv = (float*)(g2t + (size_t)3072 * 768);
    float* meanv = sqv + 8192;
    float* Avec = meanv + 8192;
    float* Cvec = Avec + 768;
    float* bqkv = Cvec + 768;                   // concat bias [2304]

    // fused prologue: 7 transposes + rowstat + precomp + meanv=0 + bqkv concat
    prep_all<<<15716, 256, 0, stream>>>(se_w2, sw2t, wq, wqt, wk, wkt, wv, wvt,
                                        wo, wot, gw1, g1t, gw2, g2t,
                                        x, xb, sqv, bq, bk, bv, bqkv, meanv,
                                        dp_w, dp_b, se_w1, se_b1, Avec, Cvec);

    // Gram -> distance row-sums (batch-per-XCD, L2-resident)
    gemm_bt<EPI_GRAM, 128><<<dim3(8, 8, 8), 256, 0, stream>>>(xb, xb, 1024, 1024, 768,
                                                              nullptr, nullptr, nullptr, nullptr, sqv, meanv);
    hgen<<<8192, 256, 0, stream>>>(meanv, Avec, Cvec, hsp);
    // x = x + h @ se_w2 + se_b2  -> d_out (fp32 residual stream)
    gemm4<EPI_RES><<<dim3(64, 6), 256, 0, stream>>>(hsp, sw2t, 8192, 768, 768,
                                                    se_b2, x, out, nullptr);
    // attention block
    lnorm<<<8192, 256, 0, stream>>>(out, n1g, n1b, xb);
    gemm4<EPI_QKV><<<dim3(64, 18), 256, 0, stream>>>(xb, wqt, 8192, 2304, 768,
                                                     bqkv, nullptr, nullptr, q_);
    flash_attn<<<dim3(8, 12, 8), 256, 0, stream>>>(q_, k_, v_, o_);
    gemm4<EPI_RES><<<dim3(64, 6), 256, 0, stream>>>(o_, wot, 8192, 768, 768,
                                                    bo, out, out, nullptr);
    // FFN block
    lnorm<<<8192, 256, 0, stream>>>(out, n2g, n2b, xb);
    gemm4<EPI_GELU><<<dim3(64, 24), 256, 0, stream>>>(xb, g1t, 8192, 3072, 768,
                                                      gb1, nullptr, nullptr, hff);
    // FFN2 on gemm8 (r12-measured 81.7us vs gemm4-splitK 84.3us)
    gemm8<EPI_RES><<<dim3(32, 6), 512, 0, stream>>>(hff, g2t, 8192, 768, 3072,
                                                    gb2, out, out, nullptr);
}

// Round 19
// 390.948 us; speedup vs baseline: 1.0162x; 1.0162x over previous
//
#include <hip/hip_runtime.h>
#include <hip/hip_bf16.h>

typedef unsigned short ushort;
typedef __attribute__((ext_vector_type(8))) __bf16 bf16x8;
typedef __attribute__((ext_vector_type(4))) float f32x4;
typedef __attribute__((ext_vector_type(8))) ushort ushort8;

__device__ inline ushort f2bf(float f) {
    union { float f; unsigned u; } a{f};
    unsigned r = a.u + 0x7FFFu + ((a.u >> 16) & 1u);
    return (ushort)(r >> 16);
}
__device__ inline float gelu_f(float x) {
    return 0.5f * x * (1.f + erff(x * 0.70710678118654752f));
}

// ---------------- fused prologue: transposes + rowstat + precomp + init ----
__global__ void prep_all(const float* __restrict__ se_w2, ushort* __restrict__ sw2t,
                         const float* __restrict__ wq, ushort* __restrict__ wqt,
                         const float* __restrict__ wk, ushort* __restrict__ wkt,
                         const float* __restrict__ wv, ushort* __restrict__ wvt,
                         const float* __restrict__ wo, ushort* __restrict__ wot,
                         const float* __restrict__ gw1, ushort* __restrict__ g1t,
                         const float* __restrict__ gw2, ushort* __restrict__ g2t,
                         const float* __restrict__ x, ushort* __restrict__ xb,
                         float* __restrict__ sq,
                         const float* __restrict__ bq, const float* __restrict__ bk,
                         const float* __restrict__ bv, float* __restrict__ bqkv,
                         float* __restrict__ meanv,
                         const float* __restrict__ dp_w, const float* __restrict__ dp_b,
                         const float* __restrict__ se_w1, const float* __restrict__ se_b1,
                         float* __restrict__ Avec, float* __restrict__ Cvec) {
    __shared__ float tile[32][33];
    __shared__ float wsum[4];
    int bid = blockIdx.x;
    int tid = threadIdx.x;
    if (bid < 7488) {
        const float* Wm; ushort* Wt; int K, N, kx, ny;
        if (bid < 2880) {
            int task = bid / 576, tt = bid % 576;
            kx = tt % 24; ny = tt / 24; K = 768; N = 768;
            switch (task) {
                case 0: Wm = se_w2; Wt = sw2t; break;
                case 1: Wm = wq; Wt = wqt; break;
                case 2: Wm = wk; Wt = wkt; break;
                case 3: Wm = wv; Wt = wvt; break;
                default: Wm = wo; Wt = wot; break;
            }
        } else if (bid < 5184) {
            int tt = bid - 2880; kx = tt % 24; ny = tt / 24; K = 768; N = 3072;
            Wm = gw1; Wt = g1t;
        } else {
            int tt = bid - 5184; kx = tt % 96; ny = tt / 96; K = 3072; N = 768;
            Wm = gw2; Wt = g2t;
        }
        int k0 = kx * 32, n0 = ny * 32;
        int tx = tid & 31, ty = tid >> 5;
        #pragma unroll
        for (int r = ty; r < 32; r += 8) tile[r][tx] = Wm[(size_t)(k0 + r) * N + n0 + tx];
        __syncthreads();
        #pragma unroll
        for (int r = ty; r < 32; r += 8) Wt[(size_t)(n0 + r) * K + k0 + tx] = f2bf(tile[tx][r]);
    } else if (bid < 15680) {
        int row = bid - 7488;
        const float* xr = x + (size_t)row * 768;
        ushort* xbr = xb + (size_t)row * 768;
        float s = 0.f;
        #pragma unroll
        for (int i = 0; i < 3; ++i) {
            float vv = xr[tid + i * 256];
            xbr[tid + i * 256] = f2bf(vv);
            s += vv * vv;
        }
        #pragma unroll
        for (int off = 1; off < 64; off <<= 1) s += __shfl_xor(s, off);
        if ((tid & 63) == 0) wsum[tid >> 6] = s;
        __syncthreads();
        if (tid == 0) sq[row] = wsum[0] + wsum[1] + wsum[2] + wsum[3];
    } else if (bid < 15683) {
        int o = (bid - 15680) * 256 + tid;
        float a = 0.f, c = 0.f;
        for (int i = 0; i < 192; ++i) {
            float w = se_w1[(size_t)i * 768 + o];
            a += dp_w[i] * w;
            c += dp_b[i] * w;
        }
        Avec[o] = a;
        Cvec[o] = c + se_b1[o];
    } else if (bid < 15715) {
        meanv[(bid - 15683) * 256 + tid] = 0.f;
    } else {
        for (int i = tid; i < 2304; i += 256) {
            float v = (i < 768) ? bq[i] : (i < 1536 ? bk[i - 768] : bv[i - 1536]);
            bqkv[i] = v;
        }
    }
}

// ---------------- spatial h generation (rank-1 + gelu) ---------------------
__global__ void hgen(const float* __restrict__ mean_acc, const float* __restrict__ Avec,
                     const float* __restrict__ Cvec, ushort* __restrict__ h) {
    int row = blockIdx.x;
    float md = mean_acc[row] * (1.f / 1024.f);
    int t = threadIdx.x;
    #pragma unroll
    for (int i = 0; i < 3; ++i) {
        int o = t + i * 256;
        h[(size_t)row * 768 + o] = f2bf(gelu_f(md * Avec[o] + Cvec[o]));
    }
}

// ---------------- layernorm fp32 -> bf16 -----------------------------------
__global__ void lnorm(const float* __restrict__ xin, const float* __restrict__ g,
                      const float* __restrict__ b, ushort* __restrict__ xn) {
    int row = blockIdx.x;
    const float* xr = xin + (size_t)row * 768;
    int t = threadIdx.x;
    float v[3];
    float s = 0.f, s2 = 0.f;
    #pragma unroll
    for (int i = 0; i < 3; ++i) {
        v[i] = xr[t + i * 256];
        s += v[i];
        s2 += v[i] * v[i];
    }
    #pragma unroll
    for (int off = 1; off < 64; off <<= 1) { s += __shfl_xor(s, off); s2 += __shfl_xor(s2, off); }
    __shared__ float a0[4], a1[4];
    if ((t & 63) == 0) { a0[t >> 6] = s; a1[t >> 6] = s2; }
    __syncthreads();
    s = a0[0] + a0[1] + a0[2] + a0[3];
    s2 = a1[0] + a1[1] + a1[2] + a1[3];
    float mu = s * (1.f / 768.f);
    float var = s2 * (1.f / 768.f) - mu * mu;
    float rs = rsqrtf(var + 1e-5f);
    #pragma unroll
    for (int i = 0; i < 3; ++i) {
        int o = t + i * 256;
        xn[(size_t)row * 768 + o] = f2bf((v[i] - mu) * rs * g[o] + b[o]);
    }
}

// ---------------- MFMA GEMM (2-phase, 128-tile): used for Gram only --------
#define BM 128
#define BK 32

enum { EPI_BF16 = 0, EPI_GELU = 1, EPI_RES = 2, EPI_GRAM = 3, EPI_QKV = 4 };

template <int EPI, int BNT>
__launch_bounds__(256, BNT == 64 ? 4 : 2)
__global__ void gemm_bt(const ushort* __restrict__ A, const ushort* __restrict__ Bt,
                        int M, int N, int K,
                        const float* __restrict__ bias,
                        const float* res, float* outf,
                        ushort* __restrict__ outh,
                        const float* __restrict__ sq, float* __restrict__ mean_acc) {
    __shared__ __align__(16) ushort As[2][BM * BK];
    __shared__ __align__(16) ushort Bs[2][BNT * BK];

    unsigned gx = gridDim.x, gy = gridDim.y;
    unsigned flat = blockIdx.x + gx * (blockIdx.y + gy * blockIdx.z);
    unsigned total = gx * gy * gridDim.z;
    unsigned chunk = total >> 3;
    flat = (flat & 7) * chunk + (flat >> 3);
    unsigned bx = flat % gx;
    unsigned rem = flat / gx;
    unsigned by = rem % gy;
    unsigned bz = rem / gy;

    int m0 = bx * BM;
    int n0 = by * BNT;
    if (EPI == EPI_GRAM) {
        A += (size_t)bz * 1024 * 768;
        Bt = A;
        sq += bz * 1024;
        mean_acc += bz * 1024;
    }
    int t = threadIdx.x, w = t >> 6, l = t & 63;
    int lg = l >> 4, li = l & 15;
    constexpr int MI = (BNT == 128) ? 4 : 2;
    int wm = (BNT == 128) ? (w >> 1) * 64 : w * 32;
    int wn = (BNT == 128) ? (w & 1) * 64 : 0;

    int srow = l >> 2, scol = (l & 3) * 8;
    const ushort* agp0 = A + (size_t)(m0 + (2 * w) * 16 + srow) * K + scol;
    const ushort* agp1 = A + (size_t)(m0 + (2 * w + 1) * 16 + srow) * K + scol;
    const ushort* bgp0;
    const ushort* bgp1 = nullptr;
    ushort* la0 = &As[0][(2 * w) * 16 * BK];
    ushort* lb0;
    if (BNT == 128) {
        bgp0 = Bt + (size_t)(n0 + (2 * w) * 16 + srow) * K + scol;
        bgp1 = Bt + (size_t)(n0 + (2 * w + 1) * 16 + srow) * K + scol;
        lb0 = &Bs[0][(2 * w) * 16 * BK];
    } else {
        bgp0 = Bt + (size_t)(n0 + w * 16 + srow) * K + scol;
        lb0 = &Bs[0][w * 16 * BK];
    }

    f32x4 acc[MI][4] = {};

    auto stage = [&](int buf, int kt) {
        size_t ko = (size_t)kt * BK;
        ushort* la = la0 + buf * (BM * BK);
        ushort* lb = lb0 + buf * (BNT * BK);
        __builtin_amdgcn_global_load_lds((const __attribute__((address_space(1))) void*)(agp0 + ko),
                                         (__attribute__((address_space(3))) void*)la, 16, 0, 0);
        __builtin_amdgcn_global_load_lds((const __attribute__((address_space(1))) void*)(agp1 + ko),
                                         (__attribute__((address_space(3))) void*)(la + 16 * BK), 16, 0, 0);
        __builtin_amdgcn_global_load_lds((const __attribute__((address_space(1))) void*)(bgp0 + ko),
                                         (__attribute__((address_space(3))) void*)lb, 16, 0, 0);
        if (BNT == 128)
            __builtin_amdgcn_global_load_lds((const __attribute__((address_space(1))) void*)(bgp1 + ko),
                                             (__attribute__((address_space(3))) void*)(lb + 16 * BK), 16, 0, 0);
    };

    int nk = K / BK;
    stage(0, 0);
    __syncthreads();
    int buf = 0;
    for (int kt = 0; kt < nk; ++kt) {
        if (kt + 1 < nk) stage(buf ^ 1, kt + 1);
        bf16x8 af[MI], bfr[4];
        #pragma unroll
        for (int i = 0; i < MI; ++i)
            af[i] = *reinterpret_cast<const bf16x8*>(&As[buf][(wm + i * 16 + li) * BK + lg * 8]);
        #pragma unroll
        for (int i = 0; i < 4; ++i)
            bfr[i] = *reinterpret_cast<const bf16x8*>(&Bs[buf][(wn + i * 16 + li) * BK + lg * 8]);
        #pragma unroll
        for (int mi = 0; mi < MI; ++mi)
            #pragma unroll
            for (int ni = 0; ni < 4; ++ni)
                acc[mi][ni] = __builtin_amdgcn_mfma_f32_16x16x32_bf16(af[mi], bfr[ni], acc[mi][ni], 0, 0, 0);
        __syncthreads();
        buf ^= 1;
    }

    #pragma unroll
    for (int mi = 0; mi < MI; ++mi) {
        #pragma unroll
        for (int r = 0; r < 4; ++r) {
            int row = m0 + wm + mi * 16 + lg * 4 + r;
            if (EPI == EPI_GRAM) {
                float si = sq[row];
                float s = 0.f;
                #pragma unroll
                for (int ni = 0; ni < 4; ++ni) {
                    int col = n0 + wn + ni * 16 + li;
                    float d2 = si + sq[col] - 2.f * acc[mi][ni][r];
                    s += sqrtf(fmaxf(d2, 0.f));
                }
                s += __shfl_xor(s, 1); s += __shfl_xor(s, 2);
                s += __shfl_xor(s, 4); s += __shfl_xor(s, 8);
                if (li == 0) atomicAdd(&mean_acc[row], s);
            } else {
                #pragma unroll
                for (int ni = 0; ni < 4; ++ni) {
                    int col = n0 + wn + ni * 16 + li;
                    float v = acc[mi][ni][r] + bias[col];
                    if (EPI == EPI_BF16) outh[(size_t)row * N + col] = f2bf(v);
                    if (EPI == EPI_GELU) outh[(size_t)row * N + col] = f2bf(gelu_f(v));
                    if (EPI == EPI_RES) outf[(size_t)row * N + col] = res[(size_t)row * N + col] + v;
                    if (EPI == EPI_QKV) {
                        int which = col / 768;
                        int c2 = col - which * 768;
                        outh[(size_t)which * (8192 * 768) + (size_t)row * 768 + c2] = f2bf(v);
                    }
                }
            }
        }
    }
}

// ---------------- gemm4p: 128x128, m-split XCD, 3 blocks/CU, PIPELINED -----
// Used for K=768 GEMMs (se_w2, QKV, wo, FFN1). Conflicts measured 0.
template <int EPI>
__launch_bounds__(256, 3)
__global__ void gemm4(const ushort* __restrict__ A, const ushort* __restrict__ Bt,
                      int M, int N, int K,
                      const float* __restrict__ bias,
                      const float* res, float* outf, ushort* __restrict__ outh) {
    __shared__ __align__(16) ushort As[3][128 * 32];
    __shared__ __align__(16) ushort Bs[3][128 * 32];

    unsigned gx = gridDim.x, gy = gridDim.y;
    unsigned orig = blockIdx.x + gx * (blockIdx.y + gy * blockIdx.z);
    unsigned xcd = orig & 7;
    unsigned q = orig >> 3;
    unsigned mpg = gx >> 3;
    unsigned mloc = q % mpg;
    unsigned rest = q / mpg;
    unsigned n = rest % gy;
    int m0 = (xcd * mpg + mloc) * 128;
    int n0 = n * 128;

    int t = threadIdx.x, w = t >> 6, l = t & 63;
    int lg = l >> 4, li = l & 15;
    int wm = (w >> 1) * 64, wn = (w & 1) * 64;

    int srow = l >> 2;
    int scol = ((l & 3) ^ ((l >> 3) & 3)) * 8;
    const ushort* agp0 = A + (size_t)(m0 + (2 * w) * 16 + srow) * K + scol;
    const ushort* agp1 = A + (size_t)(m0 + (2 * w + 1) * 16 + srow) * K + scol;
    const ushort* bgp0 = Bt + (size_t)(n0 + (2 * w) * 16 + srow) * K + scol;
    const ushort* bgp1 = Bt + (size_t)(n0 + (2 * w + 1) * 16 + srow) * K + scol;

    f32x4 acc[4][4] = {};

    auto stage = [&](int buf, int kt) {
        size_t ko = (size_t)kt * 32;
        ushort* la = &As[buf][(2 * w) * 16 * 32];
        ushort* lb = &Bs[buf][(2 * w) * 16 * 32];
        __builtin_amdgcn_global_load_lds((const __attribute__((address_space(1))) void*)(agp0 + ko),
                                         (__attribute__((address_space(3))) void*)la, 16, 0, 0);
        __builtin_amdgcn_global_load_lds((const __attribute__((address_space(1))) void*)(agp1 + ko),
                                         (__attribute__((address_space(3))) void*)(la + 16 * 32), 16, 0, 0);
        __builtin_amdgcn_global_load_lds((const __attribute__((address_space(1))) void*)(bgp0 + ko),
                                         (__attribute__((address_space(3))) void*)lb, 16, 0, 0);
        __builtin_amdgcn_global_load_lds((const __attribute__((address_space(1))) void*)(bgp1 + ko),
                                         (__attribute__((address_space(3))) void*)(lb + 16 * 32), 16, 0, 0);
    };

    int nk = K / 32;
    stage(0, 0);
    stage(1, 1);
    int rdsw = (lg ^ ((li >> 1) & 3)) * 8;
    for (int kt = 0; kt < nk; ++kt) {
        int buf = kt % 3;
        if (kt + 1 < nk) asm volatile("s_waitcnt vmcnt(4)" ::: "memory");
        else             asm volatile("s_waitcnt vmcnt(0)" ::: "memory");
        asm volatile("s_barrier" ::: "memory");
        __builtin_amdgcn_sched_barrier(0);
        bf16x8 af[4], bfr[4];
        #pragma unroll
        for (int i = 0; i < 4; ++i) {
            af[i] = *reinterpret_cast<const bf16x8*>(&As[buf][(wm + i * 16 + li) * 32 + rdsw]);
            bfr[i] = *reinterpret_cast<const bf16x8*>(&Bs[buf][(wn + i * 16 + li) * 32 + rdsw]);
        }
        __builtin_amdgcn_s_setprio(1);
        #pragma unroll
        for (int mi = 0; mi < 4; ++mi)
            #pragma unroll
            for (int ni = 0; ni < 4; ++ni)
                acc[mi][ni] = __builtin_amdgcn_mfma_f32_16x16x32_bf16(af[mi], bfr[ni], acc[mi][ni], 0, 0, 0);
        __builtin_amdgcn_s_setprio(0);
        if (kt + 2 < nk) stage((kt + 2) % 3, kt + 2);
    }

    #pragma unroll
    for (int mi = 0; mi < 4; ++mi) {
        #pragma unroll
        for (int r = 0; r < 4; ++r) {
            int row = m0 + wm + mi * 16 + lg * 4 + r;
            #pragma unroll
            for (int ni = 0; ni < 4; ++ni) {
                int col = n0 + wn + ni * 16 + li;
                float v = acc[mi][ni][r] + bias[col];
                if (EPI == EPI_GELU) outh[(size_t)row * N + col] = f2bf(gelu_f(v));
                if (EPI == EPI_RES)  outf[(size_t)row * N + col] = res[(size_t)row * N + col] + v;
                if (EPI == EPI_QKV) {
                    int which = col / 768;
                    int c2 = col - which * 768;
                    outh[(size_t)which * (8192 * 768) + (size_t)row * 768 + c2] = f2bf(v);
                }
            }
        }
    }
}

// ---------------- gemm8 (r12-proven, 81.7us on FFN2): 256x128, BK=64 -------
template <int EPI>
__launch_bounds__(512, 2)
__global__ void gemm8(const ushort* __restrict__ A, const ushort* __restrict__ Bt,
                      int M, int N, int K,
                      const float* __restrict__ bias,
                      const float* res, float* outf, ushort* __restrict__ outh) {
    __shared__ __align__(16) ushort As[3][2][128 * 64];
    __shared__ __align__(16) ushort Bs[3][2][64 * 64];

    unsigned gx = gridDim.x;                       // 32 m-tiles
    unsigned orig = blockIdx.x + gx * blockIdx.y;
    unsigned xcd = orig & 7;
    unsigned q = orig >> 3;
    unsigned mpg = gx >> 3;                        // 4 m-tiles per XCD
    unsigned mloc = q % mpg;
    unsigned n = q / mpg;
    int m0 = (xcd * mpg + mloc) * 256;
    int n0 = n * 128;

    int t = threadIdx.x, w = t >> 6, l = t & 63;
    int lg = l >> 4, li = l & 15;
    int wr = w >> 1, wc = w & 1;
    int ha = wr >> 1;
    int ra = (wr & 1) * 64;

    f32x4 acc[4][4] = {};

    auto stage = [&](int buf, int kt) {
        int k0 = kt * 64;
        #pragma unroll
        for (int h = 0; h < 2; ++h) {
            #pragma unroll
            for (int jj = 0; jj < 2; ++jj) {
                int d = (2 * w + jj) * 1024 + l * 16;
                int dp = d ^ (((d >> 7) & 7) << 4);
                const ushort* src = A + (size_t)(m0 + h * 128 + (dp >> 7)) * K + k0 + ((dp & 127) >> 1);
                __builtin_amdgcn_global_load_lds(
                    (const __attribute__((address_space(1))) void*)src,
                    (__attribute__((address_space(3))) void*)&As[buf][h][(2 * w + jj) * 512], 16, 0, 0);
            }
            {
                int d = w * 1024 + l * 16;
                int dp = d ^ (((d >> 7) & 7) << 4);
                const ushort* src = Bt + (size_t)(n0 + h * 64 + (dp >> 7)) * K + k0 + ((dp & 127) >> 1);
                __builtin_amdgcn_global_load_lds(
                    (const __attribute__((address_space(1))) void*)src,
                    (__attribute__((address_space(3))) void*)&Bs[buf][h][w * 512], 16, 0, 0);
            }
        }
    };

    int nk = K / 64;
    stage(0, 0);
    stage(1, 1);
    stage(2, 2);
    for (int kt = 0; kt < nk; ++kt) {
        int buf = kt % 3;
        if (kt + 2 < nk)      asm volatile("s_waitcnt vmcnt(12)" ::: "memory");
        else if (kt + 1 < nk) asm volatile("s_waitcnt vmcnt(6)" ::: "memory");
        else                  asm volatile("s_waitcnt vmcnt(0)" ::: "memory");
        asm volatile("s_barrier" ::: "memory");
        __builtin_amdgcn_sched_barrier(0);
        #pragma unroll
        for (int kk = 0; kk < 2; ++kk) {
            bf16x8 af[4], bf[4];
            #pragma unroll
            for (int mi = 0; mi < 4; ++mi) {
                int e = (ra + mi * 16 + li) * 128 + kk * 64 + lg * 16;
                int ep = e ^ (((e >> 7) & 7) << 4);
                af[mi] = *reinterpret_cast<const bf16x8*>(&As[buf][ha][ep >> 1]);
            }
            #pragma unroll
            for (int ni = 0; ni < 4; ++ni) {
                int e = (ni * 16 + li) * 128 + kk * 64 + lg * 16;
                int ep = e ^ (((e >> 7) & 7) << 4);
                bf[ni] = *reinterpret_cast<const bf16x8*>(&Bs[buf][wc][ep >> 1]);
            }
            __builtin_amdgcn_s_setprio(1);
            #pragma unroll
            for (int mi = 0; mi < 4; ++mi)
                #pragma unroll
                for (int ni = 0; ni < 4; ++ni)
                    acc[mi][ni] = __builtin_amdgcn_mfma_f32_16x16x32_bf16(af[mi], bf[ni], acc[mi][ni], 0, 0, 0);
            __builtin_amdgcn_s_setprio(0);
        }
        asm volatile("s_barrier" ::: "memory");
        __builtin_amdgcn_sched_barrier(0);
        if (kt + 3 < nk) stage(buf, kt + 3);
    }

    #pragma unroll
    for (int mi = 0; mi < 4; ++mi) {
        #pragma unroll
        for (int r = 0; r < 4; ++r) {
            int row = m0 + wr * 64 + mi * 16 + lg * 4 + r;
            #pragma unroll
            for (int ni = 0; ni < 4; ++ni) {
                int col = n0 + wc * 64 + ni * 16 + li;
                float v = acc[mi][ni][r] + bias[col];
                if (EPI == EPI_GELU) outh[(size_t)row * N + col] = f2bf(gelu_f(v));
                if (EPI == EPI_RES)  outf[(size_t)row * N + col] = res[(size_t)row * N + col] + v;
            }
        }
    }
}

// ---------------- flash attention (r17-best): exp-domain, K-LDS staged -----
// grid (8, 12, 8); 4 waves; K via global_load_lds dbuf; ones-MFMA ell;
// defer-max; setprio.
__launch_bounds__(256, 3)
__global__ void flash_attn(const ushort* __restrict__ q, const ushort* __restrict__ k,
                           const ushort* __restrict__ v, ushort* __restrict__ o) {
    int flat = blockIdx.x + 8 * (blockIdx.y + 12 * blockIdx.z);
    flat = (flat & 7) * 96 + (flat >> 3);
    int qt = flat & 7;
    int rem = flat >> 3;
    int h = rem % 12;
    int b = rem / 12;

    int t = threadIdx.x, w = t >> 6, l = t & 63;
    int lg = l >> 4, li = l & 15;

    __shared__ __align__(16) ushort Vt[2][64][72];  // V^T tile, stride 144B
    __shared__ __align__(16) ushort P[4][32][72];   // per-wave P[q][kv]
    __shared__ __align__(16) ushort Ks[2][64 * 64]; // K tile, chunk-swizzled

    const size_t hoff = (size_t)h * 64;
    const size_t bbase = (size_t)b * 1024 * 768;
    const ushort* kbase = &k[bbase + hoff];

    bf16x8 qf[2][2];
    #pragma unroll
    for (int f = 0; f < 2; ++f) {
        int qrow = qt * 128 + w * 32 + f * 16 + li;
        const ushort* qp = &q[bbase + (size_t)qrow * 768 + hoff];
        qf[f][0] = *reinterpret_cast<const bf16x8*>(qp + lg * 8);
        qf[f][1] = *reinterpret_cast<const bf16x8*>(qp + 32 + lg * 8);
    }

    bf16x8 onesf;
    #pragma unroll
    for (int i = 0; i < 8; ++i) onesf[i] = (__bf16)1.0f;

    float m_[2][4];
    f32x4 oacc[2][4];
    f32x4 oell[2];
    #pragma unroll
    for (int f = 0; f < 2; ++f) {
        #pragma unroll
        for (int r = 0; r < 4; ++r) m_[f][r] = -1e30f;
        oell[f] = f32x4{0.f, 0.f, 0.f, 0.f};
        #pragma unroll
        for (int n = 0; n < 4; ++n) oacc[f][n] = f32x4{0.f, 0.f, 0.f, 0.f};
    }

    int vrow = t & 63;
    int vc = t >> 6;
    const ushort* vbase = &v[bbase + hoff];

    auto stageK = [&](int kbuf, int jtile) {
        #pragma unroll
        for (int j = 0; j < 2; ++j) {
            int c = (w * 2 + j) * 64 + l;
            int krow = c >> 3, kcc = c & 7;
            int srcc = (kcc & 4) | ((kcc & 3) ^ (krow & 3));
            const ushort* src = &kbase[(size_t)(jtile * 64 + krow) * 768 + srcc * 8];
            __builtin_amdgcn_global_load_lds(
                (const __attribute__((address_space(1))) void*)src,
                (__attribute__((address_space(3))) void*)&Ks[kbuf][c * 8], 16, 0, 0);
        }
    };

    stageK(0, 0);
    ushort8 vv0 = *reinterpret_cast<const ushort8*>(&vbase[(size_t)vrow * 768 + vc * 8]);
    ushort8 vv1 = *reinterpret_cast<const ushort8*>(&vbase[(size_t)vrow * 768 + (vc + 4) * 8]);
    __syncthreads();

    int kch = lg ^ (li & 3);

    for (int jt = 0; jt < 16; ++jt) {
        int j0 = jt * 64, buf = jt & 1;
        #pragma unroll
        for (int i = 0; i < 8; ++i) Vt[buf][vc * 8 + i][vrow] = vv0[i];
        #pragma unroll
        for (int i = 0; i < 8; ++i) Vt[buf][(vc + 4) * 8 + i][vrow] = vv1[i];
        if (jt < 15) {
            vv0 = *reinterpret_cast<const ushort8*>(&vbase[(size_t)(j0 + 64 + vrow) * 768 + vc * 8]);
            vv1 = *reinterpret_cast<const ushort8*>(&vbase[(size_t)(j0 + 64 + vrow) * 768 + (vc + 4) * 8]);
            stageK(buf ^ 1, jt + 1);
        }
        f32x4 s[2][4];
        __builtin_amdgcn_s_setprio(1);
        #pragma unroll
        for (int jj = 0; jj < 4; ++jj) {
            int krow = jj * 16 + li;
            bf16x8 kf0 = *reinterpret_cast<const bf16x8*>(&Ks[buf][krow * 64 + kch * 8]);
            bf16x8 kf1 = *reinterpret_cast<const bf16x8*>(&Ks[buf][krow * 64 + 32 + kch * 8]);
            #pragma unroll
            for (int f = 0; f < 2; ++f) {
                f32x4 a = {0.f, 0.f, 0.f, 0.f};
                a = __builtin_amdgcn_mfma_f32_16x16x32_bf16(qf[f][0], kf0, a, 0, 0, 0);
                a = __builtin_amdgcn_mfma_f32_16x16x32_bf16(qf[f][1], kf1, a, 0, 0, 0);
                s[f][jj] = a * 0.125f;
            }
        }
        __builtin_amdgcn_s_setprio(0);
        #pragma unroll
        for (int f = 0; f < 2; ++f) {
            float mt[4];
            #pragma unroll
            for (int r = 0; r < 4; ++r)
                mt[r] = fmaxf(fmaxf(s[f][0][r], s[f][1][r]), fmaxf(s[f][2][r], s[f][3][r]));
            #pragma unroll
            for (int r = 0; r < 4; ++r) {
                mt[r] = fmaxf(mt[r], __shfl_xor(mt[r], 1));
                mt[r] = fmaxf(mt[r], __shfl_xor(mt[r], 2));
                mt[r] = fmaxf(mt[r], __shfl_xor(mt[r], 4));
                mt[r] = fmaxf(mt[r], __shfl_xor(mt[r], 8));
            }
            bool need = (mt[0] > m_[f][0] + 8.f) | (mt[1] > m_[f][1] + 8.f) |
                        (mt[2] > m_[f][2] + 8.f) | (mt[3] > m_[f][3] + 8.f);
            if (__any(need)) {
                #pragma unroll
                for (int r = 0; r < 4; ++r) {
                    float mn = fmaxf(m_[f][r], mt[r]);
                    float al = __expf(m_[f][r] - mn);
                    m_[f][r] = mn;
                    #pragma unroll
                    for (int n = 0; n < 4; ++n) oacc[f][n][r] *= al;
                    oell[f][r] *= al;
                }
            }
            #pragma unroll
            for (int jj = 0; jj < 4; ++jj)
                #pragma unroll
                for (int r = 0; r < 4; ++r)
                    P[w][f * 16 + lg * 4 + r][jj * 16 + li] = f2bf(__expf(s[f][jj][r] - m_[f][r]));
        }
        __syncthreads();   // drains K-DMA for jt+1; orders Vt/P
        bf16x8 pf[2][2];
        #pragma unroll
        for (int f = 0; f < 2; ++f) {
            pf[f][0] = *reinterpret_cast<const bf16x8*>(&P[w][f * 16 + li][lg * 8]);
            pf[f][1] = *reinterpret_cast<const bf16x8*>(&P[w][f * 16 + li][32 + lg * 8]);
        }
        __builtin_amdgcn_s_setprio(1);
        #pragma unroll
        for (int f = 0; f < 2; ++f) {
            oell[f] = __builtin_amdgcn_mfma_f32_16x16x32_bf16(pf[f][0], onesf, oell[f], 0, 0, 0);
            oell[f] = __builtin_amdgcn_mfma_f32_16x16x32_bf16(pf[f][1], onesf, oell[f], 0, 0, 0);
        }
        #pragma unroll
        for (int n = 0; n < 4; ++n) {
            bf16x8 vf0 = *reinterpret_cast<const bf16x8*>(&Vt[buf][n * 16 + li][lg * 8]);
            bf16x8 vf1 = *reinterpret_cast<const bf16x8*>(&Vt[buf][n * 16 + li][32 + lg * 8]);
            #pragma unroll
            for (int f = 0; f < 2; ++f) {
                oacc[f][n] = __builtin_amdgcn_mfma_f32_16x16x32_bf16(pf[f][0], vf0, oacc[f][n], 0, 0, 0);
                oacc[f][n] = __builtin_amdgcn_mfma_f32_16x16x32_bf16(pf[f][1], vf1, oacc[f][n], 0, 0, 0);
            }
        }
        __builtin_amdgcn_s_setprio(0);
    }
    #pragma unroll
    for (int f = 0; f < 2; ++f)
        #pragma unroll
        for (int n = 0; n < 4; ++n)
            #pragma unroll
            for (int r = 0; r < 4; ++r) {
                int row = qt * 128 + w * 32 + f * 16 + lg * 4 + r;
                o[bbase + (size_t)row * 768 + hoff + n * 16 + li] = f2bf(oacc[f][n][r] / oell[f][r]);
            }
}

// ---------------------------------------------------------------------------
extern "C" void kernel_launch(void* const* d_in, const int* in_sizes, int n_in,
                              void* d_out, int out_size, void* d_ws, size_t ws_size,
                              hipStream_t stream) {
    const float* x = (const float*)d_in[0];
    const float* dp_w = (const float*)d_in[1];
    const float* dp_b = (const float*)d_in[2];
    const float* se_w1 = (const float*)d_in[3];
    const float* se_b1 = (const float*)d_in[4];
    const float* se_w2 = (const float*)d_in[5];
    const float* se_b2 = (const float*)d_in[6];
    const float* wq = (const float*)d_in[7];  const float* bq = (const float*)d_in[8];
    const float* wk = (const float*)d_in[9];  const float* bk = (const float*)d_in[10];
    const float* wv = (const float*)d_in[11]; const float* bv = (const float*)d_in[12];
    const float* wo = (const float*)d_in[13]; const float* bo = (const float*)d_in[14];
    const float* gw1 = (const float*)d_in[15]; const float* gb1 = (const float*)d_in[16];
    const float* gw2 = (const float*)d_in[17]; const float* gb2 = (const float*)d_in[18];
    const float* n1g = (const float*)d_in[19]; const float* n1b = (const float*)d_in[20];
    const float* n2g = (const float*)d_in[21]; const float* n2b = (const float*)d_in[22];
    float* out = (float*)d_out;

    constexpr size_t SZ_ACT = (size_t)8192 * 768 * 2;  // bytes per bf16 activation
    char* W = (char*)d_ws;
    ushort* xb = (ushort*)(W);                  // bf16 x; later reused as xn
    ushort* q_ = (ushort*)(W + SZ_ACT);
    ushort* k_ = (ushort*)(W + 2 * SZ_ACT);
    ushort* v_ = (ushort*)(W + 3 * SZ_ACT);
    ushort* o_ = (ushort*)(W + 4 * SZ_ACT);
    ushort* hsp = q_;
    ushort* hff = q_;
    ushort* wqt = (ushort*)(W + 5 * SZ_ACT);    // contiguous qkv weight [2304][768]
    ushort* wkt = wqt + (size_t)768 * 768;
    ushort* wvt = wkt + (size_t)768 * 768;
    ushort* wot = wvt + (size_t)768 * 768;
    ushort* sw2t = wot + (size_t)768 * 768;
    ushort* g1t = sw2t + (size_t)768 * 768;
    ushort* g2t = g1t + (size_t)768 * 3072;
    float* sqv = (float*)(g2t + (size_t)3072 * 768);
    float* meanv = sqv + 8192;
    float* Avec = meanv + 8192;
    float* Cvec = Avec + 768;
    float* bqkv = Cvec + 768;                   // concat bias [2304]

    // fused prologue: 7 transposes + rowstat + precomp + meanv=0 + bqkv concat
    prep_all<<<15716, 256, 0, stream>>>(se_w2, sw2t, wq, wqt, wk, wkt, wv, wvt,
                                        wo, wot, gw1, g1t, gw2, g2t,
                                        x, xb, sqv, bq, bk, bv, bqkv, meanv,
                                        dp_w, dp_b, se_w1, se_b1, Avec, Cvec);

    // Gram -> distance row-sums (batch-per-XCD, L2-resident)
    gemm_bt<EPI_GRAM, 128><<<dim3(8, 8, 8), 256, 0, stream>>>(xb, xb, 1024, 1024, 768,
                                                              nullptr, nullptr, nullptr, nullptr, sqv, meanv);
    hgen<<<8192, 256, 0, stream>>>(meanv, Avec, Cvec, hsp);
    // x = x + h @ se_w2 + se_b2  -> d_out (fp32 residual stream)
    gemm4<EPI_RES><<<dim3(64, 6), 256, 0, stream>>>(hsp, sw2t, 8192, 768, 768,
                                                    se_b2, x, out, nullptr);
    // attention block
    lnorm<<<8192, 256, 0, stream>>>(out, n1g, n1b, xb);
    gemm4<EPI_QKV><<<dim3(64, 18), 256, 0, stream>>>(xb, wqt, 8192, 2304, 768,
                                                     bqkv, nullptr, nullptr, q_);
    flash_attn<<<dim3(8, 12, 8), 256, 0, stream>>>(q_, k_, v_, o_);
    gemm4<EPI_RES><<<dim3(64, 6), 256, 0, stream>>>(o_, wot, 8192, 768, 768,
                                                    bo, out, out, nullptr);
    // FFN block
    lnorm<<<8192, 256, 0, stream>>>(out, n2g, n2b, xb);
    gemm4<EPI_GELU><<<dim3(64, 24), 256, 0, stream>>>(xb, g1t, 8192, 3072, 768,
                                                      gb1, nullptr, nullptr, hff);
    // FFN2 on gemm8 (r12/r18-measured 81.7us vs gemm4-splitK 84.3us)
    gemm8<EPI_RES><<<dim3(32, 6), 512, 0, stream>>>(hff, g2t, 8192, 768, 3072,
                                                    gb2, out, out, nullptr);
}